// Round 21
// baseline (325.008 us; speedup 1.0000x reference)
//
#include <hip/hip_runtime.h>
#include <math.h>

#define D_   1024
#define H_   16
#define DH_  64
#define T_   1024
#define B_   2
#define P_   4
#define L_   2052      // P + 2T
#define WIN_ 256
#define MH_  4096
#define FF_  4096

typedef __attribute__((ext_vector_type(8))) short bf16x8;
typedef __attribute__((ext_vector_type(4))) float f32x4;
typedef __attribute__((ext_vector_type(8))) unsigned short ush8;

__device__ __forceinline__ unsigned short f2bf(float f) {
  unsigned int u = __builtin_bit_cast(unsigned int, f);
  u += 0x7fffu + ((u >> 16) & 1u);           // round to nearest even
  return (unsigned short)(u >> 16);
}
__device__ __forceinline__ float bf2f(unsigned short h) {
  unsigned int u = ((unsigned int)h) << 16;
  return __builtin_bit_cast(float, u);
}

// async global -> LDS, 16B per lane. LDS dest must be wave-uniform base; lane i
// lands at base + i*16B. Global src is per-lane.
__device__ __forceinline__ void gl16(const unsigned short* g, unsigned short* l) {
  __builtin_amdgcn_global_load_lds(
      (const __attribute__((address_space(1))) unsigned int*)g,
      (__attribute__((address_space(3))) unsigned int*)l, 16, 0, 0);
}

// ---------------- fused fp32 -> bf16 conversion (7 buffers, one launch) ----------------
__global__ __launch_bounds__(256)
void cvt7_k(const float* s0, unsigned short* d0, int n0,
            const float* s1, unsigned short* d1, int n1,
            const float* s2, unsigned short* d2, int n2,
            const float* s3, unsigned short* d3, int n3,
            const float* s4, unsigned short* d4, int n4,
            const float* s5, unsigned short* d5, int n5,
            const float* s6, unsigned short* d6, int n6) {
  const float* s; unsigned short* d; int n;
  switch (blockIdx.y) {
    case 0: s = s0; d = d0; n = n0; break;
    case 1: s = s1; d = d1; n = n1; break;
    case 2: s = s2; d = d2; n = n2; break;
    case 3: s = s3; d = d3; n = n3; break;
    case 4: s = s4; d = d4; n = n4; break;
    case 5: s = s5; d = d5; n = n5; break;
    default: s = s6; d = d6; n = n6; break;
  }
  int e = (blockIdx.x * 256 + threadIdx.x) * 4;
  if (e >= n) return;
  float4 v = *(const float4*)(s + e);
  ushort4 o;
  o.x = f2bf(v.x); o.y = f2bf(v.y); o.z = f2bf(v.z); o.w = f2bf(v.w);
  *(ushort4*)(d + e) = o;
}

// ---- fused concat + gemm2 4-way split-K reduce + LN1 ----
__global__ __launch_bounds__(256)
void concat_ln1_k(const float* __restrict__ x, const float* __restrict__ pmem,
                  const float* __restrict__ p0, const float* __restrict__ p1,
                  const float* __restrict__ p2, const float* __restrict__ p3,
                  const float* __restrict__ mb2, const float* __restrict__ g,
                  const float* __restrict__ bb,
                  float* __restrict__ aug, unsigned short* __restrict__ hln) {
  const int row = blockIdx.x;
  const int rl  = row % L_;
  const int b   = row / L_;
  const int tid = threadIdx.x;
  const int c   = tid * 4;
  float4 v;
  if (rl < P_) {
    v = *(const float4*)(pmem + rl * D_ + c);
  } else if (rl < P_ + T_) {
    size_t idx = (size_t)(b * T_ + (rl - P_)) * D_ + c;
    float4 a0 = *(const float4*)(p0 + idx);
    float4 a1 = *(const float4*)(p1 + idx);
    float4 a2 = *(const float4*)(p2 + idx);
    float4 a3 = *(const float4*)(p3 + idx);
    float4 bbv = *(const float4*)(mb2 + c);
    v = make_float4(a0.x + a1.x + a2.x + a3.x + bbv.x,
                    a0.y + a1.y + a2.y + a3.y + bbv.y,
                    a0.z + a1.z + a2.z + a3.z + bbv.z,
                    a0.w + a1.w + a2.w + a3.w + bbv.w);
  } else {
    v = *(const float4*)(x + (size_t)(b * T_ + (rl - P_ - T_)) * D_ + c);
  }
  *(float4*)(aug + (size_t)row * D_ + c) = v;
  float s  = v.x + v.y + v.z + v.w;
  float sq = v.x * v.x + v.y * v.y + v.z * v.z + v.w * v.w;
  #pragma unroll
  for (int o = 1; o < 64; o <<= 1) { s += __shfl_xor(s, o); sq += __shfl_xor(sq, o); }
  __shared__ float red[8];
  const int wid = tid >> 6;
  if ((tid & 63) == 0) { red[wid] = s; red[4 + wid] = sq; }
  __syncthreads();
  s  = red[0] + red[1] + red[2] + red[3];
  sq = red[4] + red[5] + red[6] + red[7];
  const float mean = s * (1.0f / D_);
  const float var  = sq * (1.0f / D_) - mean * mean;
  const float inv  = rsqrtf(var + 1e-5f);
  float4 gv = *(const float4*)(g + c);
  float4 bv = *(const float4*)(bb + c);
  unsigned short* dst = hln + (size_t)row * D_ + c;
  dst[0] = f2bf((v.x - mean) * inv * gv.x + bv.x);
  dst[1] = f2bf((v.y - mean) * inv * gv.y + bv.y);
  dst[2] = f2bf((v.z - mean) * inv * gv.z + bv.z);
  dst[3] = f2bf((v.w - mean) * inv * gv.w + bv.w);
}

// ---- gemm10 4-way split-K reduce (bf16 partials): out = sum(q) + fb2 + hres ----
__global__ void reduce10_k(const unsigned short* __restrict__ q0,
                           const unsigned short* __restrict__ q1,
                           const unsigned short* __restrict__ q2,
                           const unsigned short* __restrict__ q3,
                           const float* __restrict__ hres, const float* __restrict__ fb2,
                           float* __restrict__ out) {
  int i = blockIdx.x * blockDim.x + threadIdx.x;
  if (i >= (B_ * L_ * D_) / 4) return;
  int e = i * 4;
  int d = e % D_;
  ushort4 u0 = *(const ushort4*)(q0 + e);
  ushort4 u1 = *(const ushort4*)(q1 + e);
  ushort4 u2 = *(const ushort4*)(q2 + e);
  ushort4 u3 = *(const ushort4*)(q3 + e);
  float4 hr = *(const float4*)(hres + e);
  float4 bb = *(const float4*)(fb2 + d);
  float4 v;
  v.x = bf2f(u0.x) + bf2f(u1.x) + bf2f(u2.x) + bf2f(u3.x) + hr.x + bb.x;
  v.y = bf2f(u0.y) + bf2f(u1.y) + bf2f(u2.y) + bf2f(u3.y) + hr.y + bb.y;
  v.z = bf2f(u0.z) + bf2f(u1.z) + bf2f(u2.z) + bf2f(u3.z) + hr.z + bb.z;
  v.w = bf2f(u0.w) + bf2f(u1.w) + bf2f(u2.w) + bf2f(u3.w) + hr.w + bb.w;
  *(float4*)(out + e) = v;
}

// ---------------- layernorm (D=1024), bf16 out ----------------
__global__ __launch_bounds__(256)
void layernorm_k(const float* __restrict__ in, const float* __restrict__ g,
                 const float* __restrict__ bb, unsigned short* __restrict__ out) {
  const int row = blockIdx.x;
  const int tid = threadIdx.x;
  const float* xr = in + (size_t)row * D_;
  float4 v = *(const float4*)(xr + tid * 4);
  float s  = v.x + v.y + v.z + v.w;
  float sq = v.x * v.x + v.y * v.y + v.z * v.z + v.w * v.w;
  #pragma unroll
  for (int o = 1; o < 64; o <<= 1) { s += __shfl_xor(s, o); sq += __shfl_xor(sq, o); }
  __shared__ float red[8];
  const int wid = tid >> 6;
  if ((tid & 63) == 0) { red[wid] = s; red[4 + wid] = sq; }
  __syncthreads();
  s  = red[0] + red[1] + red[2] + red[3];
  sq = red[4] + red[5] + red[6] + red[7];
  const float mean = s * (1.0f / D_);
  const float var  = sq * (1.0f / D_) - mean * mean;
  const float inv  = rsqrtf(var + 1e-5f);
  const int c = tid * 4;
  float4 gv = *(const float4*)(g + c);
  float4 bv = *(const float4*)(bb + c);
  unsigned short* dst = out + (size_t)row * D_ + c;
  dst[0] = f2bf((v.x - mean) * inv * gv.x + bv.x);
  dst[1] = f2bf((v.y - mean) * inv * gv.y + bv.y);
  dst[2] = f2bf((v.z - mean) * inv * gv.z + bv.z);
  dst[3] = f2bf((v.w - mean) * inv * gv.w + bv.w);
}

// ---------------- bf16 MFMA GEMM: C = epi(A[M,K] @ W[N,K]^T + bias) ----------
// phi-SWIZZLED LDS (bank-conflict-free, coalescing-preserving): lane u stages
// (row=u>>2, kq=(u&3)^((u>>3)&3)); read unit u=4*fr+(fkq^((fr>>1)&3)).
// 2-buffer distance-2 pipeline, counted vmcnt (never 0 in loop), setprio on MFMA.
// bf16 epilogue via per-wave LDS transpose -> 2x16B dwordx4 stores per lane.
// PART=1: grid-z K-split partials at Cv + (z&1)*zs1 + (z>>1)*zs2.
// SWZ=1: row-panel-resident XCD ordering (nwg % 8 == 0 required).
// GRID RULE (measured): keep >= 2 blocks/CU — grid-starved dispatches double
// their latency-bound step time (gemm1 fat 256-blk == gemm9's time at 2x FLOPs).
template<int ACT, int OUTBF, int RESID, int WM, int WN, int NWR, int NWC, int KS, int PART, int SWZ>
__global__ __launch_bounds__(KS * NWR * NWC * 64)
void gemm_bt_k(const unsigned short* __restrict__ A,
               const unsigned short* __restrict__ W,
               const float* __restrict__ bias,
               const float* __restrict__ resid,
               void* __restrict__ Cv,
               int M, int N, int K, int ldK, long long zs1, long long zs2) {
  constexpr int NW = NWR * NWC;          // waves per group
  constexpr int BM = NWR * WM * 16;
  constexpr int BN = NWC * WN * 16;
  constexpr int LPS = BM / (NW * 16) + BN / (NW * 16);  // loads/stage/wave
  constexpr int STG = 2 * KS * (BM + BN) * 32 * 2;      // dbuf staging bytes
  constexpr int RED = (KS > 1) ? BM * BN * 4 : 0;       // reduce bytes
  constexpr int EPI = OUTBF ? (KS * NW * 16 * 72 * 2) : 0;  // epilogue transpose bytes
  constexpr int SB1 = STG > RED ? STG : RED;
  constexpr int SBYTES = SB1 > EPI ? SB1 : EPI;
  __shared__ __align__(16) char smem[SBYTES];
  unsigned short* sA = (unsigned short*)smem;            // 2*KS buffers of BM*32
  unsigned short* sB = sA + 2 * KS * BM * 32;            // 2*KS buffers of BN*32

  const int tid  = threadIdx.x;
  const int lane = tid & 63;
  const int wv   = tid >> 6;
  const int grp  = wv / NW;
  const int wg   = wv % NW;
  const int wr   = wg / NWC, wc = wg % NWC;

  int lx = blockIdx.x, ly = blockIdx.y, lz = blockIdx.z;
  if (SWZ) {
    const unsigned int gX = gridDim.x, gY = gridDim.y, gZ = gridDim.z;
    const unsigned int nwg = gX * gY * gZ;
    const unsigned int flat = (blockIdx.z * gY + blockIdx.y) * gX + blockIdx.x;
    const unsigned int q = nwg >> 3;                 // nwg % 8 == 0
    const unsigned int g = (flat & 7) * q + (flat >> 3);
    const unsigned int NC = gX * gZ;
    ly = g / NC;
    const unsigned int c = g % NC;
    lx = c / gZ;
    lz = c % gZ;
  }
  const int gm0 = ly * BM;
  const int gn0 = lx * BN;

  const int KperG = K / KS;
  const int NT    = KperG / 32;
  const int zofs  = PART ? lz * K : 0;

  const f32x4 fz = {0.f, 0.f, 0.f, 0.f};
  f32x4 acc[WM][WN];
  #pragma unroll
  for (int i = 0; i < WM; ++i)
    #pragma unroll
    for (int j = 0; j < WN; ++j) acc[i][j] = fz;

  // phi-swizzled staging map: row = lane>>2 (coalesced 64B per 4 lanes),
  // k-quarter permuted per row-pair
  const int srow = lane >> 2;
  const int skq  = (lane & 3) ^ ((lane >> 3) & 3);
  const int skc  = skq * 8;
  const unsigned short* gA = A + (size_t)(gm0 + srow) * ldK + grp * KperG + zofs + skc;
  const unsigned short* gB = W + (size_t)(gn0 + srow) * ldK + grp * KperG + zofs + skc;

  // phi-swizzled fragment read: unit u = 4*fr + (fkq ^ ((fr>>1)&3))
  const int fr   = lane & 15;
  const int fkq  = lane >> 4;
  const int fofs = (fr * 4 + (fkq ^ ((fr >> 1) & 3))) * 8;  // ushort offset in 512-blk

  auto stage = [&](int d, int k0) {
    unsigned short* dA = sA + (d * KS + grp) * BM * 32;
    unsigned short* dB = sB + (d * KS + grp) * BN * 32;
    #pragma unroll
    for (int t = 0; t < BM / (NW * 16); ++t) {
      const int rr = wg * 16 + t * NW * 16;   // multiple of 16
      gl16(gA + (size_t)rr * ldK + k0, dA + rr * 32);
    }
    #pragma unroll
    for (int t = 0; t < BN / (NW * 16); ++t) {
      const int rr = wg * 16 + t * NW * 16;
      gl16(gB + (size_t)rr * ldK + k0, dB + rr * 32);
    }
  };

  auto wait_lps = [&]() {
    if constexpr (LPS == 2)      asm volatile("s_waitcnt vmcnt(2)" ::: "memory");
    else if constexpr (LPS == 3) asm volatile("s_waitcnt vmcnt(3)" ::: "memory");
    else if constexpr (LPS == 4) asm volatile("s_waitcnt vmcnt(4)" ::: "memory");
    else                         asm volatile("s_waitcnt vmcnt(0)" ::: "memory");
  };

  stage(0, 0);
  stage(1, 32);                          // NT >= 2 always here
  wait_lps();                            // stage(0) landed (in-order counting)
  __builtin_amdgcn_s_barrier();
  asm volatile("" ::: "memory");

  for (int kt = 0; kt < NT; ++kt) {
    const int d = kt & 1;
    const unsigned short* lA = sA + (d * KS + grp) * BM * 32;
    const unsigned short* lB = sB + (d * KS + grp) * BN * 32;
    bf16x8 af[WM], bfr[WN];
    #pragma unroll
    for (int i = 0; i < WM; ++i) af[i]  = *(const bf16x8*)&lA[(wr * WM + i) * 512 + fofs];
    #pragma unroll
    for (int j = 0; j < WN; ++j) bfr[j] = *(const bf16x8*)&lB[(wc * WN + j) * 512 + fofs];
    asm volatile("s_waitcnt lgkmcnt(0)" ::: "memory");   // my reads of buf d done
    __builtin_amdgcn_s_barrier();                        // ALL waves done reading buf d
    asm volatile("" ::: "memory");
    if (kt + 2 < NT) stage(d, (kt + 2) * 32);            // overwrite buf d (safe now)
    __builtin_amdgcn_s_setprio(1);
    #pragma unroll
    for (int i = 0; i < WM; ++i)
      #pragma unroll
      for (int j = 0; j < WN; ++j)
        acc[i][j] = __builtin_amdgcn_mfma_f32_16x16x32_bf16(af[i], bfr[j], acc[i][j], 0, 0, 0);
    __builtin_amdgcn_s_setprio(0);
    if (kt + 1 < NT) {
      if (kt + 2 < NT) wait_lps();       // stage(kt+1) landed; stage(kt+2) in flight
      else asm volatile("s_waitcnt vmcnt(0)" ::: "memory");
      __builtin_amdgcn_s_barrier();
      asm volatile("" ::: "memory");
    }
  }

  // ---- cross-group K reduction (deterministic, via LDS) ----
  if (KS > 1) {
    __syncthreads();
    f32x4* sR = (f32x4*)smem;
    const int tg = tid & (NW * 64 - 1);
    for (int g = 1; g < KS; ++g) {
      if (grp == g) {
        #pragma unroll
        for (int i = 0; i < WM; ++i)
          #pragma unroll
          for (int j = 0; j < WN; ++j) sR[(tg * WM + i) * WN + j] = acc[i][j];
      }
      __syncthreads();
      if (grp == 0) {
        #pragma unroll
        for (int i = 0; i < WM; ++i)
          #pragma unroll
          for (int j = 0; j < WN; ++j) {
            f32x4 t = sR[(tg * WM + i) * WN + j];
            #pragma unroll
            for (int r = 0; r < 4; ++r) acc[i][j][r] += t[r];
          }
      }
      __syncthreads();
    }
    if (grp != 0) return;
  }

  // epilogue: C/D layout col = lane&15, row = (lane>>4)*4 + reg
  const int rq = (lane >> 4) * 4;
  if (OUTBF) {
    // LDS-transposed coalesced bf16 store (bias/act applied pre-LDS)
    __syncthreads();                                   // staging LDS dead
    unsigned short* lt = (unsigned short*)smem + wv * (16 * 72);
    unsigned short* Pb = PART
        ? (unsigned short*)((char*)Cv + (size_t)(lz & 1) * zs1 + (size_t)(lz >> 1) * zs2)
        : (unsigned short*)Cv;
    const int rrow = lane >> 2;          // 0..15
    const int cseg = (lane & 3) * 16;    // 0,16,32,48
    #pragma unroll
    for (int i = 0; i < WM; ++i) {
      #pragma unroll
      for (int j = 0; j < WN; ++j) {
        const int cl = j * 16 + fr;
        const float bcol = PART ? 0.f : bias[gn0 + wc * WN * 16 + cl];
        #pragma unroll
        for (int r = 0; r < 4; ++r) {
          float v = acc[i][j][r] + bcol;
          if (!PART) {
            if (ACT == 1) v = fmaxf(v, 0.f);
            if (ACT == 2) {
              float t = 0.7978845608f * v * (1.0f + 0.044715f * v * v);
              float e = __expf(2.0f * t);
              v = v - __fdividef(v, e + 1.0f);
            }
          }
          lt[(rq + r) * 72 + cl] = f2bf(v);
        }
      }
      const int grow = gm0 + wr * WM * 16 + i * 16 + rrow;
      const int gcol = gn0 + wc * WN * 16 + cseg;
      if (grow < M) {
        ush8 v0 = *(const ush8*)&lt[rrow * 72 + cseg];
        ush8 v1 = *(const ush8*)&lt[rrow * 72 + cseg + 8];
        unsigned short* gp = Pb + (size_t)grow * N + gcol;
        *(ush8*)gp = v0;
        *(ush8*)(gp + 8) = v1;
      }
    }
    return;
  }
  if (PART) {
    char* Pb = (char*)Cv + (size_t)(lz & 1) * zs1 + (size_t)(lz >> 1) * zs2;
    #pragma unroll
    for (int i = 0; i < WM; ++i) {
      #pragma unroll
      for (int j = 0; j < WN; ++j) {
        const int col = gn0 + wc * WN * 16 + j * 16 + fr;
        #pragma unroll
        for (int r = 0; r < 4; ++r) {
          const int row = gm0 + wr * WM * 16 + i * 16 + rq + r;
          if (row < M) ((float*)Pb)[(size_t)row * N + col] = acc[i][j][r];
        }
      }
    }
    return;
  }
  #pragma unroll
  for (int i = 0; i < WM; ++i) {
    #pragma unroll
    for (int j = 0; j < WN; ++j) {
      const int col = gn0 + wc * WN * 16 + j * 16 + fr;
      const float bcol = bias[col];
      #pragma unroll
      for (int r = 0; r < 4; ++r) {
        const int row = gm0 + wr * WM * 16 + i * 16 + rq + r;
        if (row < M) {
          float v = acc[i][j][r] + bcol;
          if (RESID) v += resid[(size_t)row * N + col];
          if (ACT == 1) v = fmaxf(v, 0.f);
          if (ACT == 2) {
            float t = 0.7978845608f * v * (1.0f + 0.044715f * v * v);
            float e = __expf(2.0f * t);
            v = v - __fdividef(v, e + 1.0f);
          }
          ((float*)Cv)[(size_t)row * N + col] = v;
        }
      }
    }
  }
}

// ---------------- MFMA sliding-window causal attention (bf16 qkv) ----------------
// grid (ceil(L/128), H, B), block 512 = 8 waves; 128 queries/block halves K/V
// staging per query.
__global__ __launch_bounds__(512)
void attn_k(const unsigned short* __restrict__ qkv, unsigned short* __restrict__ ctx) {
  __shared__ unsigned short Kb[64][72];
  __shared__ unsigned short Vt[64][72];
  __shared__ unsigned short Ps[8][16][72];
  const int tid  = threadIdx.x;
  const int lane = tid & 63;
  const int w    = tid >> 6;               // 0..7
  const int l15  = lane & 15;
  const int l4   = lane >> 4;
  const int qb   = blockIdx.x * 128;
  const int h    = blockIdx.y;
  const int b    = blockIdx.z;

  int qrow = qb + w * 16 + l15;
  if (qrow >= L_) qrow = L_ - 1;           // clamp: garbage rows masked at store
  const unsigned short* qp = qkv + ((size_t)(b * L_ + qrow)) * 3072 + h * 64;
  bf16x8 aq0, aq1;
  #pragma unroll
  for (int e = 0; e < 8; ++e) {
    aq0[e] = (short)f2bf(bf2f(qp[l4 * 8 + e]) * 0.125f);
    aq1[e] = (short)f2bf(bf2f(qp[32 + l4 * 8 + e]) * 0.125f);
  }

  const f32x4 fz = {0.f, 0.f, 0.f, 0.f};
  f32x4 acc_o[4];
  #pragma unroll
  for (int j = 0; j < 4; ++j) acc_o[j] = fz;
  float m_[4], ls[4];
  #pragma unroll
  for (int r = 0; r < 4; ++r) { m_[r] = -3.0e38f; ls[r] = 0.f; }

  int k0 = qb - WIN_;
  if (k0 < 0) k0 = 0;

  for (int kb = k0; kb <= qb + 64; kb += 64) {
    {
      const int c   = tid;                 // 0..511
      const int row = c >> 3;
      const int cc  = (c & 7) * 8;
      const int g   = kb + row;
      ush8 kv8 = {0, 0, 0, 0, 0, 0, 0, 0}, vv8 = kv8;
      if (g < L_) {
        const unsigned short* base = qkv + ((size_t)(b * L_ + g)) * 3072 + h * 64 + cc;
        kv8 = *(const ush8*)(base + 1024);
        vv8 = *(const ush8*)(base + 2048);
      }
      *(ush8*)&Kb[row][cc] = kv8;
      #pragma unroll
      for (int e = 0; e < 8; ++e) Vt[cc + e][row] = vv8[e];
    }
    __syncthreads();

    f32x4 s[4];
    #pragma unroll
    for (int kt = 0; kt < 4; ++kt) {
      bf16x8 bk0 = *(const bf16x8*)&Kb[kt * 16 + l15][l4 * 8];
      bf16x8 bk1 = *(const bf16x8*)&Kb[kt * 16 + l15][32 + l4 * 8];
      f32x4 t = __builtin_amdgcn_mfma_f32_16x16x32_bf16(aq0, bk0, fz, 0, 0, 0);
      s[kt]   = __builtin_amdgcn_mfma_f32_16x16x32_bf16(aq1, bk1, t,  0, 0, 0);
    }

    #pragma unroll
    for (int r = 0; r < 4; ++r) {
      const int qg = qb + w * 16 + l4 * 4 + r;
      float rm = -3.0e38f;
      #pragma unroll
      for (int kt = 0; kt < 4; ++kt) {
        const int kg = kb + kt * 16 + l15;
        const bool ok = (kg <= qg) && (kg + WIN_ > qg);
        rm = fmaxf(rm, ok ? s[kt][r] : -3.0e38f);
      }
      rm = fmaxf(rm, __shfl_xor(rm, 1));
      rm = fmaxf(rm, __shfl_xor(rm, 2));
      rm = fmaxf(rm, __shfl_xor(rm, 4));
      rm = fmaxf(rm, __shfl_xor(rm, 8));
      const float mn = fmaxf(m_[r], rm);
      const float sf = __expf(m_[r] - mn);
      m_[r] = mn;
      float ps = 0.f;
      #pragma unroll
      for (int kt = 0; kt < 4; ++kt) {
        const int kg = kb + kt * 16 + l15;
        const bool ok = (kg <= qg) && (kg + WIN_ > qg);
        const float p = ok ? __expf(s[kt][r] - mn) : 0.f;
        ps += p;
        Ps[w][l4 * 4 + r][kt * 16 + l15] = f2bf(p);
      }
      ps += __shfl_xor(ps, 1);
      ps += __shfl_xor(ps, 2);
      ps += __shfl_xor(ps, 4);
      ps += __shfl_xor(ps, 8);
      ls[r] = ls[r] * sf + ps;
      #pragma unroll
      for (int j = 0; j < 4; ++j) acc_o[j][r] *= sf;
    }

    #pragma unroll
    for (int ks = 0; ks < 2; ++ks) {
      bf16x8 pa = *(const bf16x8*)&Ps[w][l15][ks * 32 + l4 * 8];
      #pragma unroll
      for (int j = 0; j < 4; ++j) {
        bf16x8 vb = *(const bf16x8*)&Vt[j * 16 + l15][ks * 32 + l4 * 8];
        acc_o[j] = __builtin_amdgcn_mfma_f32_16x16x32_bf16(pa, vb, acc_o[j], 0, 0, 0);
      }
    }
    __syncthreads();
  }

  #pragma unroll
  for (int r = 0; r < 4; ++r) {
    const int qg = qb + w * 16 + l4 * 4 + r;
    if (qg < L_) {
      const float inv = 1.0f / ls[r];
      unsigned short* dst = ctx + ((size_t)(b * L_ + qg)) * 1024 + h * 64 + l15;
      #pragma unroll
      for (int j = 0; j < 4; ++j) dst[j * 16] = f2bf(acc_o[j][r] * inv);
    }
  }
}

// ---------------- launch ----------------
extern "C" void kernel_launch(void* const* d_in, const int* in_sizes, int n_in,
                              void* d_out, int out_size, void* d_ws, size_t ws_size,
                              hipStream_t stream) {
  (void)in_sizes; (void)n_in; (void)out_size; (void)ws_size;
  const float* x    = (const float*)d_in[0];
  const float* pmem = (const float*)d_in[1];
  const float* mW1  = (const float*)d_in[2];
  const float* mb1  = (const float*)d_in[3];
  const float* mW2  = (const float*)d_in[4];
  const float* mb2  = (const float*)d_in[5];
  const float* ln1g = (const float*)d_in[6];
  const float* ln1b = (const float*)d_in[7];
  const float* Wqkv = (const float*)d_in[8];
  const float* bqkv = (const float*)d_in[9];
  const float* Wo   = (const float*)d_in[10];
  const float* bo   = (const float*)d_in[11];
  const float* ln2g = (const float*)d_in[12];
  const float* ln2b = (const float*)d_in[13];
  const float* fW1  = (const float*)d_in[14];
  const float* fb1  = (const float*)d_in[15];
  const float* fW2  = (const float*)d_in[16];
  const float* fb2  = (const float*)d_in[17];
  float* outp = (float*)d_out;
  char* ws = (char*)d_ws;

  // workspace layout (bytes); total ~134.6 MB
  unsigned short* w1b   = (unsigned short*)(ws + 0ull);          // 8 MB
  unsigned short* w2b   = (unsigned short*)(ws + 8388608ull);    // 8 MB
  unsigned short* wqkvb = (unsigned short*)(ws + 16777216ull);   // 6 MB
  unsigned short* wob   = (unsigned short*)(ws + 23068672ull);   // 2 MB
  unsigned short* fw1b  = (unsigned short*)(ws + 25165824ull);   // 8 MB
  unsigned short* fw2b  = (unsigned short*)(ws + 33554432ull);   // 8 MB
  const size_t S = 41943040ull;
  float* aug  = (float*)(ws + S);                                // 4104x1024 f32
  float* hres = (float*)(ws + S + 16809984ull);                  // 4104x1024 f32
  unsigned short* hlnbuf = (unsigned short*)(ws + S + 33619968ull); // 4224x1024 bf16 (shared hln/ctx/hln2)
  char* R = ws + S + 42270720ull;                                // 50.4 MB shared region
  unsigned short* xb   = (unsigned short*)(R);                   // stage 1   (2048x1024)
  unsigned short* h1   = (unsigned short*)(R + 4194304ull);      // stages 1-2 (2048x4096, ends R+20971520)
  unsigned short* qkvb = (unsigned short*)(R);                   // stages 5-6 (4104x3072 bf16)
  unsigned short* f1   = (unsigned short*)(R + 15826944ull);     // stages 9-10 (4224x4096)
  unsigned short* hln  = hlnbuf;
  unsigned short* ctxb = hlnbuf;
  unsigned short* hln2 = hlnbuf;
  // gemm2 split-K partials (4 x 2048x1024 f32), DISJOINT from h1 (its input):
  // z0 @ hres, z1 @ hres+8.4M, z2 @ R+20971520 (past h1's end), z3 @ +8.4M.
  float* g2p = hres;
  const long long G2S  = 8404992LL;         // (z&1) stride
  const long long G2S2 = 46432256LL;        // (z>>1) stride: hres -> R+20971520
  // gemm10 split-K partials (4 x 4104x1024 bf16), two-stride:
  // z0 @ aug, z1 @ aug+8.4M, z2 @ hlnbuf, z3 @ hlnbuf+8.4M
  const long long Z10a = 8404992LL;         // (z&1) stride
  const long long Z10b = 33619968LL;        // (z>>1) stride (aug -> hlnbuf)

  const int BT = B_ * T_;   // 2048
  const int BL = B_ * L_;   // 4104
  const int NE4 = B_ * L_ * D_ / 4;

  // 0. all fp32->bf16 conversions in one launch
  cvt7_k<<<dim3((MH_ * D_ / 4 + 255) / 256, 7), 256, 0, stream>>>(
      x, xb, B_ * T_ * D_,  mW1, w1b, MH_ * D_,  mW2, w2b, D_ * MH_,
      Wqkv, wqkvb, 3 * D_ * D_,  Wo, wob, D_ * D_,
      fW1, fw1b, FF_ * D_,  fW2, fw2b, D_ * FF_);

  // 1. h1 = relu(x @ mW1^T + mb1), bf16   [128x128, 4 waves -> 512 blocks = 2/CU]
  gemm_bt_k<1, 1, 0, 4, 4, 2, 2, 1, 0, 0><<<dim3(MH_ / 128, BT / 128), 256, 0, stream>>>(xb, w1b, mb1, nullptr, h1, BT, MH_, D_, D_, 0, 0);
  // 2. split-K z=4: partials = h1 @ mW2^T (K-quarters), raw fp32 [128x128, SWZ]
  gemm_bt_k<0, 0, 0, 4, 4, 2, 2, 1, 1, 1><<<dim3(D_ / 128, BT / 128, 4), 256, 0, stream>>>(h1, w2b, nullptr, nullptr, g2p, BT, D_, MH_ / 4, MH_, G2S, G2S2);
  // 3+4. aug = concat(pers, sum(p)+mb2, x); hln = LN1(aug)
  concat_ln1_k<<<dim3(BL), 256, 0, stream>>>(x, pmem,
      g2p, (float*)((char*)g2p + G2S), (float*)((char*)g2p + G2S2), (float*)((char*)g2p + G2S + G2S2),
      mb2, ln1g, ln1b, aug, hln);
  // 5. qkv = hln @ Wqkv^T + bqkv, bf16    [128x128, 4 waves -> 792 blocks = 3/CU]
  gemm_bt_k<0, 1, 0, 4, 4, 2, 2, 1, 0, 0><<<dim3(3 * D_ / 128, (BL + 127) / 128), 256, 0, stream>>>(hln, wqkvb, bqkv, nullptr, qkvb, BL, 3 * D_, D_, D_, 0, 0);
  // 6. ctx = sliding-window attention (MFMA), bf16 [128 queries/block]
  attn_k<<<dim3((L_ + 127) / 128, H_, B_), 512, 0, stream>>>(qkvb, ctxb);
  // 7. hres = aug + ctx @ Wo^T + bo, fp32 [128x64, KS=1]
  gemm_bt_k<0, 0, 1, 2, 4, 4, 1, 1, 0, 0><<<dim3(D_ / 64, (BL + 127) / 128), 256, 0, stream>>>(ctxb, wob, bo, aug, hres, BL, D_, D_, D_, 0, 0);
  // 8. hln2 = LN2(hres), bf16
  layernorm_k<<<dim3(BL), 256, 0, stream>>>(hres, ln2g, ln2b, hln2);
  // 9. f1 = gelu(hln2 @ fW1^T + fb1), bf16 [fat 128x256, 8 waves, 528 blocks]
  gemm_bt_k<2, 1, 0, 4, 4, 2, 4, 1, 0, 0><<<dim3(FF_ / 256, (BL + 127) / 128), 512, 0, stream>>>(hln2, fw1b, fb1, nullptr, f1, BL, FF_, D_, D_, 0, 0);
  // 10a. split-K z=4: bf16 partials = f1 @ fW2^T (K-quarters) [fat 128x256, 8 waves]
  gemm_bt_k<0, 1, 0, 4, 4, 2, 4, 1, 1, 0><<<dim3(D_ / 256, (BL + 127) / 128, 4), 512, 0, stream>>>(f1, fw2b, nullptr, nullptr, (void*)aug, BL, D_, FF_ / 4, FF_, Z10a, Z10b);
  // 10b. out = sum(bf16 partials) + fb2 + hres
  reduce10_k<<<dim3((NE4 + 255) / 256), 256, 0, stream>>>(
      (const unsigned short*)aug,
      (const unsigned short*)((char*)aug + Z10a),
      (const unsigned short*)((char*)aug + Z10b),
      (const unsigned short*)((char*)aug + Z10a + Z10b),
      hres, fb2, outp);
}

// Round 22
// 319.629 us; speedup vs baseline: 1.0168x; 1.0168x over previous
//
#include <hip/hip_runtime.h>
#include <math.h>

#define D_   1024
#define H_   16
#define DH_  64
#define T_   1024
#define B_   2
#define P_   4
#define L_   2052      // P + 2T
#define WIN_ 256
#define MH_  4096
#define FF_  4096

typedef __attribute__((ext_vector_type(8))) short bf16x8;
typedef __attribute__((ext_vector_type(4))) float f32x4;
typedef __attribute__((ext_vector_type(8))) unsigned short ush8;

__device__ __forceinline__ unsigned short f2bf(float f) {
  unsigned int u = __builtin_bit_cast(unsigned int, f);
  u += 0x7fffu + ((u >> 16) & 1u);           // round to nearest even
  return (unsigned short)(u >> 16);
}
__device__ __forceinline__ float bf2f(unsigned short h) {
  unsigned int u = ((unsigned int)h) << 16;
  return __builtin_bit_cast(float, u);
}

// async global -> LDS, 16B per lane. LDS dest must be wave-uniform base; lane i
// lands at base + i*16B. Global src is per-lane.
__device__ __forceinline__ void gl16(const unsigned short* g, unsigned short* l) {
  __builtin_amdgcn_global_load_lds(
      (const __attribute__((address_space(1))) unsigned int*)g,
      (__attribute__((address_space(3))) unsigned int*)l, 16, 0, 0);
}

// ---------------- fused fp32 -> bf16 conversion (7 buffers, one launch) ----------------
__global__ __launch_bounds__(256)
void cvt7_k(const float* s0, unsigned short* d0, int n0,
            const float* s1, unsigned short* d1, int n1,
            const float* s2, unsigned short* d2, int n2,
            const float* s3, unsigned short* d3, int n3,
            const float* s4, unsigned short* d4, int n4,
            const float* s5, unsigned short* d5, int n5,
            const float* s6, unsigned short* d6, int n6) {
  const float* s; unsigned short* d; int n;
  switch (blockIdx.y) {
    case 0: s = s0; d = d0; n = n0; break;
    case 1: s = s1; d = d1; n = n1; break;
    case 2: s = s2; d = d2; n = n2; break;
    case 3: s = s3; d = d3; n = n3; break;
    case 4: s = s4; d = d4; n = n4; break;
    case 5: s = s5; d = d5; n = n5; break;
    default: s = s6; d = d6; n = n6; break;
  }
  int e = (blockIdx.x * 256 + threadIdx.x) * 4;
  if (e >= n) return;
  float4 v = *(const float4*)(s + e);
  ushort4 o;
  o.x = f2bf(v.x); o.y = f2bf(v.y); o.z = f2bf(v.z); o.w = f2bf(v.w);
  *(ushort4*)(d + e) = o;
}

// ---- fused concat + gemm2 4-way split-K reduce + LN1 ----
__global__ __launch_bounds__(256)
void concat_ln1_k(const float* __restrict__ x, const float* __restrict__ pmem,
                  const float* __restrict__ p0, const float* __restrict__ p1,
                  const float* __restrict__ p2, const float* __restrict__ p3,
                  const float* __restrict__ mb2, const float* __restrict__ g,
                  const float* __restrict__ bb,
                  float* __restrict__ aug, unsigned short* __restrict__ hln) {
  const int row = blockIdx.x;
  const int rl  = row % L_;
  const int b   = row / L_;
  const int tid = threadIdx.x;
  const int c   = tid * 4;
  float4 v;
  if (rl < P_) {
    v = *(const float4*)(pmem + rl * D_ + c);
  } else if (rl < P_ + T_) {
    size_t idx = (size_t)(b * T_ + (rl - P_)) * D_ + c;
    float4 a0 = *(const float4*)(p0 + idx);
    float4 a1 = *(const float4*)(p1 + idx);
    float4 a2 = *(const float4*)(p2 + idx);
    float4 a3 = *(const float4*)(p3 + idx);
    float4 bbv = *(const float4*)(mb2 + c);
    v = make_float4(a0.x + a1.x + a2.x + a3.x + bbv.x,
                    a0.y + a1.y + a2.y + a3.y + bbv.y,
                    a0.z + a1.z + a2.z + a3.z + bbv.z,
                    a0.w + a1.w + a2.w + a3.w + bbv.w);
  } else {
    v = *(const float4*)(x + (size_t)(b * T_ + (rl - P_ - T_)) * D_ + c);
  }
  *(float4*)(aug + (size_t)row * D_ + c) = v;
  float s  = v.x + v.y + v.z + v.w;
  float sq = v.x * v.x + v.y * v.y + v.z * v.z + v.w * v.w;
  #pragma unroll
  for (int o = 1; o < 64; o <<= 1) { s += __shfl_xor(s, o); sq += __shfl_xor(sq, o); }
  __shared__ float red[8];
  const int wid = tid >> 6;
  if ((tid & 63) == 0) { red[wid] = s; red[4 + wid] = sq; }
  __syncthreads();
  s  = red[0] + red[1] + red[2] + red[3];
  sq = red[4] + red[5] + red[6] + red[7];
  const float mean = s * (1.0f / D_);
  const float var  = sq * (1.0f / D_) - mean * mean;
  const float inv  = rsqrtf(var + 1e-5f);
  float4 gv = *(const float4*)(g + c);
  float4 bv = *(const float4*)(bb + c);
  unsigned short* dst = hln + (size_t)row * D_ + c;
  dst[0] = f2bf((v.x - mean) * inv * gv.x + bv.x);
  dst[1] = f2bf((v.y - mean) * inv * gv.y + bv.y);
  dst[2] = f2bf((v.z - mean) * inv * gv.z + bv.z);
  dst[3] = f2bf((v.w - mean) * inv * gv.w + bv.w);
}

// ---- gemm10 4-way split-K reduce (bf16 partials): out = sum(q) + fb2 + hres ----
__global__ void reduce10_k(const unsigned short* __restrict__ q0,
                           const unsigned short* __restrict__ q1,
                           const unsigned short* __restrict__ q2,
                           const unsigned short* __restrict__ q3,
                           const float* __restrict__ hres, const float* __restrict__ fb2,
                           float* __restrict__ out) {
  int i = blockIdx.x * blockDim.x + threadIdx.x;
  if (i >= (B_ * L_ * D_) / 4) return;
  int e = i * 4;
  int d = e % D_;
  ushort4 u0 = *(const ushort4*)(q0 + e);
  ushort4 u1 = *(const ushort4*)(q1 + e);
  ushort4 u2 = *(const ushort4*)(q2 + e);
  ushort4 u3 = *(const ushort4*)(q3 + e);
  float4 hr = *(const float4*)(hres + e);
  float4 bb = *(const float4*)(fb2 + d);
  float4 v;
  v.x = bf2f(u0.x) + bf2f(u1.x) + bf2f(u2.x) + bf2f(u3.x) + hr.x + bb.x;
  v.y = bf2f(u0.y) + bf2f(u1.y) + bf2f(u2.y) + bf2f(u3.y) + hr.y + bb.y;
  v.z = bf2f(u0.z) + bf2f(u1.z) + bf2f(u2.z) + bf2f(u3.z) + hr.z + bb.z;
  v.w = bf2f(u0.w) + bf2f(u1.w) + bf2f(u2.w) + bf2f(u3.w) + hr.w + bb.w;
  *(float4*)(out + e) = v;
}

// ---------------- layernorm (D=1024), bf16 out ----------------
__global__ __launch_bounds__(256)
void layernorm_k(const float* __restrict__ in, const float* __restrict__ g,
                 const float* __restrict__ bb, unsigned short* __restrict__ out) {
  const int row = blockIdx.x;
  const int tid = threadIdx.x;
  const float* xr = in + (size_t)row * D_;
  float4 v = *(const float4*)(xr + tid * 4);
  float s  = v.x + v.y + v.z + v.w;
  float sq = v.x * v.x + v.y * v.y + v.z * v.z + v.w * v.w;
  #pragma unroll
  for (int o = 1; o < 64; o <<= 1) { s += __shfl_xor(s, o); sq += __shfl_xor(sq, o); }
  __shared__ float red[8];
  const int wid = tid >> 6;
  if ((tid & 63) == 0) { red[wid] = s; red[4 + wid] = sq; }
  __syncthreads();
  s  = red[0] + red[1] + red[2] + red[3];
  sq = red[4] + red[5] + red[6] + red[7];
  const float mean = s * (1.0f / D_);
  const float var  = sq * (1.0f / D_) - mean * mean;
  const float inv  = rsqrtf(var + 1e-5f);
  const int c = tid * 4;
  float4 gv = *(const float4*)(g + c);
  float4 bv = *(const float4*)(bb + c);
  unsigned short* dst = out + (size_t)row * D_ + c;
  dst[0] = f2bf((v.x - mean) * inv * gv.x + bv.x);
  dst[1] = f2bf((v.y - mean) * inv * gv.y + bv.y);
  dst[2] = f2bf((v.z - mean) * inv * gv.z + bv.z);
  dst[3] = f2bf((v.w - mean) * inv * gv.w + bv.w);
}

// ---------------- bf16 MFMA GEMM: C = epi(A[M,K] @ W[N,K]^T + bias) ----------
// phi-SWIZZLED LDS (bank-conflict-free, coalescing-preserving): lane u stages
// (row=u>>2, kq=(u&3)^((u>>3)&3)); read unit u=4*fr+(fkq^((fr>>1)&3)).
// 2-buffer distance-2 pipeline, counted vmcnt (never 0 in loop), setprio on MFMA.
// bf16 epilogue via per-wave LDS transpose -> 2x16B dwordx4 stores per lane.
// PART=1: grid-z K-split partials at Cv + (z&1)*zs1 + (z>>1)*zs2.
// SWZ=1: row-panel-resident XCD ordering (nwg % 8 == 0 required).
template<int ACT, int OUTBF, int RESID, int WM, int WN, int NWR, int NWC, int KS, int PART, int SWZ>
__global__ __launch_bounds__(KS * NWR * NWC * 64)
void gemm_bt_k(const unsigned short* __restrict__ A,
               const unsigned short* __restrict__ W,
               const float* __restrict__ bias,
               const float* __restrict__ resid,
               void* __restrict__ Cv,
               int M, int N, int K, int ldK, long long zs1, long long zs2) {
  constexpr int NW = NWR * NWC;          // waves per group
  constexpr int BM = NWR * WM * 16;
  constexpr int BN = NWC * WN * 16;
  constexpr int LPS = BM / (NW * 16) + BN / (NW * 16);  // loads/stage/wave
  constexpr int STG = 2 * KS * (BM + BN) * 32 * 2;      // dbuf staging bytes
  constexpr int RED = (KS > 1) ? BM * BN * 4 : 0;       // reduce bytes
  constexpr int EPI = OUTBF ? (KS * NW * 16 * 72 * 2) : 0;  // epilogue transpose bytes
  constexpr int SB1 = STG > RED ? STG : RED;
  constexpr int SBYTES = SB1 > EPI ? SB1 : EPI;
  __shared__ __align__(16) char smem[SBYTES];
  unsigned short* sA = (unsigned short*)smem;            // 2*KS buffers of BM*32
  unsigned short* sB = sA + 2 * KS * BM * 32;            // 2*KS buffers of BN*32

  const int tid  = threadIdx.x;
  const int lane = tid & 63;
  const int wv   = tid >> 6;
  const int grp  = wv / NW;
  const int wg   = wv % NW;
  const int wr   = wg / NWC, wc = wg % NWC;

  int lx = blockIdx.x, ly = blockIdx.y, lz = blockIdx.z;
  if (SWZ) {
    const unsigned int gX = gridDim.x, gY = gridDim.y, gZ = gridDim.z;
    const unsigned int nwg = gX * gY * gZ;
    const unsigned int flat = (blockIdx.z * gY + blockIdx.y) * gX + blockIdx.x;
    const unsigned int q = nwg >> 3;                 // nwg % 8 == 0
    const unsigned int g = (flat & 7) * q + (flat >> 3);
    const unsigned int NC = gX * gZ;
    ly = g / NC;
    const unsigned int c = g % NC;
    lx = c / gZ;
    lz = c % gZ;
  }
  const int gm0 = ly * BM;
  const int gn0 = lx * BN;

  const int KperG = K / KS;
  const int NT    = KperG / 32;
  const int zofs  = PART ? lz * K : 0;

  const f32x4 fz = {0.f, 0.f, 0.f, 0.f};
  f32x4 acc[WM][WN];
  #pragma unroll
  for (int i = 0; i < WM; ++i)
    #pragma unroll
    for (int j = 0; j < WN; ++j) acc[i][j] = fz;

  // phi-swizzled staging map: row = lane>>2 (coalesced 64B per 4 lanes),
  // k-quarter permuted per row-pair
  const int srow = lane >> 2;
  const int skq  = (lane & 3) ^ ((lane >> 3) & 3);
  const int skc  = skq * 8;
  const unsigned short* gA = A + (size_t)(gm0 + srow) * ldK + grp * KperG + zofs + skc;
  const unsigned short* gB = W + (size_t)(gn0 + srow) * ldK + grp * KperG + zofs + skc;

  // phi-swizzled fragment read: unit u = 4*fr + (fkq ^ ((fr>>1)&3))
  const int fr   = lane & 15;
  const int fkq  = lane >> 4;
  const int fofs = (fr * 4 + (fkq ^ ((fr >> 1) & 3))) * 8;  // ushort offset in 512-blk

  auto stage = [&](int d, int k0) {
    unsigned short* dA = sA + (d * KS + grp) * BM * 32;
    unsigned short* dB = sB + (d * KS + grp) * BN * 32;
    #pragma unroll
    for (int t = 0; t < BM / (NW * 16); ++t) {
      const int rr = wg * 16 + t * NW * 16;   // multiple of 16
      gl16(gA + (size_t)rr * ldK + k0, dA + rr * 32);
    }
    #pragma unroll
    for (int t = 0; t < BN / (NW * 16); ++t) {
      const int rr = wg * 16 + t * NW * 16;
      gl16(gB + (size_t)rr * ldK + k0, dB + rr * 32);
    }
  };

  auto wait_lps = [&]() {
    if constexpr (LPS == 2)      asm volatile("s_waitcnt vmcnt(2)" ::: "memory");
    else if constexpr (LPS == 3) asm volatile("s_waitcnt vmcnt(3)" ::: "memory");
    else if constexpr (LPS == 4) asm volatile("s_waitcnt vmcnt(4)" ::: "memory");
    else                         asm volatile("s_waitcnt vmcnt(0)" ::: "memory");
  };

  stage(0, 0);
  stage(1, 32);                          // NT >= 2 always here
  wait_lps();                            // stage(0) landed (in-order counting)
  __builtin_amdgcn_s_barrier();
  asm volatile("" ::: "memory");

  for (int kt = 0; kt < NT; ++kt) {
    const int d = kt & 1;
    const unsigned short* lA = sA + (d * KS + grp) * BM * 32;
    const unsigned short* lB = sB + (d * KS + grp) * BN * 32;
    bf16x8 af[WM], bfr[WN];
    #pragma unroll
    for (int i = 0; i < WM; ++i) af[i]  = *(const bf16x8*)&lA[(wr * WM + i) * 512 + fofs];
    #pragma unroll
    for (int j = 0; j < WN; ++j) bfr[j] = *(const bf16x8*)&lB[(wc * WN + j) * 512 + fofs];
    asm volatile("s_waitcnt lgkmcnt(0)" ::: "memory");   // my reads of buf d done
    __builtin_amdgcn_s_barrier();                        // ALL waves done reading buf d
    asm volatile("" ::: "memory");
    if (kt + 2 < NT) stage(d, (kt + 2) * 32);            // overwrite buf d (safe now)
    __builtin_amdgcn_s_setprio(1);
    #pragma unroll
    for (int i = 0; i < WM; ++i)
      #pragma unroll
      for (int j = 0; j < WN; ++j)
        acc[i][j] = __builtin_amdgcn_mfma_f32_16x16x32_bf16(af[i], bfr[j], acc[i][j], 0, 0, 0);
    __builtin_amdgcn_s_setprio(0);
    if (kt + 1 < NT) {
      if (kt + 2 < NT) wait_lps();       // stage(kt+1) landed; stage(kt+2) in flight
      else asm volatile("s_waitcnt vmcnt(0)" ::: "memory");
      __builtin_amdgcn_s_barrier();
      asm volatile("" ::: "memory");
    }
  }

  // ---- cross-group K reduction (deterministic, via LDS) ----
  if (KS > 1) {
    __syncthreads();
    f32x4* sR = (f32x4*)smem;
    const int tg = tid & (NW * 64 - 1);
    for (int g = 1; g < KS; ++g) {
      if (grp == g) {
        #pragma unroll
        for (int i = 0; i < WM; ++i)
          #pragma unroll
          for (int j = 0; j < WN; ++j) sR[(tg * WM + i) * WN + j] = acc[i][j];
      }
      __syncthreads();
      if (grp == 0) {
        #pragma unroll
        for (int i = 0; i < WM; ++i)
          #pragma unroll
          for (int j = 0; j < WN; ++j) {
            f32x4 t = sR[(tg * WM + i) * WN + j];
            #pragma unroll
            for (int r = 0; r < 4; ++r) acc[i][j][r] += t[r];
          }
      }
      __syncthreads();
    }
    if (grp != 0) return;
  }

  // epilogue: C/D layout col = lane&15, row = (lane>>4)*4 + reg
  const int rq = (lane >> 4) * 4;
  if (OUTBF) {
    // LDS-transposed coalesced bf16 store (bias/act applied pre-LDS)
    __syncthreads();                                   // staging LDS dead
    unsigned short* lt = (unsigned short*)smem + wv * (16 * 72);
    unsigned short* Pb = PART
        ? (unsigned short*)((char*)Cv + (size_t)(lz & 1) * zs1 + (size_t)(lz >> 1) * zs2)
        : (unsigned short*)Cv;
    const int rrow = lane >> 2;          // 0..15
    const int cseg = (lane & 3) * 16;    // 0,16,32,48
    #pragma unroll
    for (int i = 0; i < WM; ++i) {
      #pragma unroll
      for (int j = 0; j < WN; ++j) {
        const int cl = j * 16 + fr;
        const float bcol = PART ? 0.f : bias[gn0 + wc * WN * 16 + cl];
        #pragma unroll
        for (int r = 0; r < 4; ++r) {
          float v = acc[i][j][r] + bcol;
          if (!PART) {
            if (ACT == 1) v = fmaxf(v, 0.f);
            if (ACT == 2) {
              float t = 0.7978845608f * v * (1.0f + 0.044715f * v * v);
              float e = __expf(2.0f * t);
              v = v - __fdividef(v, e + 1.0f);
            }
          }
          lt[(rq + r) * 72 + cl] = f2bf(v);
        }
      }
      const int grow = gm0 + wr * WM * 16 + i * 16 + rrow;
      const int gcol = gn0 + wc * WN * 16 + cseg;
      if (grow < M) {
        ush8 v0 = *(const ush8*)&lt[rrow * 72 + cseg];
        ush8 v1 = *(const ush8*)&lt[rrow * 72 + cseg + 8];
        unsigned short* gp = Pb + (size_t)grow * N + gcol;
        *(ush8*)gp = v0;
        *(ush8*)(gp + 8) = v1;
      }
    }
    return;
  }
  if (PART) {
    char* Pb = (char*)Cv + (size_t)(lz & 1) * zs1 + (size_t)(lz >> 1) * zs2;
    #pragma unroll
    for (int i = 0; i < WM; ++i) {
      #pragma unroll
      for (int j = 0; j < WN; ++j) {
        const int col = gn0 + wc * WN * 16 + j * 16 + fr;
        #pragma unroll
        for (int r = 0; r < 4; ++r) {
          const int row = gm0 + wr * WM * 16 + i * 16 + rq + r;
          if (row < M) ((float*)Pb)[(size_t)row * N + col] = acc[i][j][r];
        }
      }
    }
    return;
  }
  #pragma unroll
  for (int i = 0; i < WM; ++i) {
    #pragma unroll
    for (int j = 0; j < WN; ++j) {
      const int col = gn0 + wc * WN * 16 + j * 16 + fr;
      const float bcol = bias[col];
      #pragma unroll
      for (int r = 0; r < 4; ++r) {
        const int row = gm0 + wr * WM * 16 + i * 16 + rq + r;
        if (row < M) {
          float v = acc[i][j][r] + bcol;
          if (RESID) v += resid[(size_t)row * N + col];
          if (ACT == 1) v = fmaxf(v, 0.f);
          if (ACT == 2) {
            float t = 0.7978845608f * v * (1.0f + 0.044715f * v * v);
            float e = __expf(2.0f * t);
            v = v - __fdividef(v, e + 1.0f);
          }
          ((float*)Cv)[(size_t)row * N + col] = v;
        }
      }
    }
  }
}

// ---------------- MFMA sliding-window causal attention (bf16 qkv) ----------------
// grid (ceil(L/128), H, B), block 512 = 8 waves; 128 queries/block halves K/V
// staging per query.
__global__ __launch_bounds__(512)
void attn_k(const unsigned short* __restrict__ qkv, unsigned short* __restrict__ ctx) {
  __shared__ unsigned short Kb[64][72];
  __shared__ unsigned short Vt[64][72];
  __shared__ unsigned short Ps[8][16][72];
  const int tid  = threadIdx.x;
  const int lane = tid & 63;
  const int w    = tid >> 6;               // 0..7
  const int l15  = lane & 15;
  const int l4   = lane >> 4;
  const int qb   = blockIdx.x * 128;
  const int h    = blockIdx.y;
  const int b    = blockIdx.z;

  int qrow = qb + w * 16 + l15;
  if (qrow >= L_) qrow = L_ - 1;           // clamp: garbage rows masked at store
  const unsigned short* qp = qkv + ((size_t)(b * L_ + qrow)) * 3072 + h * 64;
  bf16x8 aq0, aq1;
  #pragma unroll
  for (int e = 0; e < 8; ++e) {
    aq0[e] = (short)f2bf(bf2f(qp[l4 * 8 + e]) * 0.125f);
    aq1[e] = (short)f2bf(bf2f(qp[32 + l4 * 8 + e]) * 0.125f);
  }

  const f32x4 fz = {0.f, 0.f, 0.f, 0.f};
  f32x4 acc_o[4];
  #pragma unroll
  for (int j = 0; j < 4; ++j) acc_o[j] = fz;
  float m_[4], ls[4];
  #pragma unroll
  for (int r = 0; r < 4; ++r) { m_[r] = -3.0e38f; ls[r] = 0.f; }

  int k0 = qb - WIN_;
  if (k0 < 0) k0 = 0;

  for (int kb = k0; kb <= qb + 64; kb += 64) {
    {
      const int c   = tid;                 // 0..511
      const int row = c >> 3;
      const int cc  = (c & 7) * 8;
      const int g   = kb + row;
      ush8 kv8 = {0, 0, 0, 0, 0, 0, 0, 0}, vv8 = kv8;
      if (g < L_) {
        const unsigned short* base = qkv + ((size_t)(b * L_ + g)) * 3072 + h * 64 + cc;
        kv8 = *(const ush8*)(base + 1024);
        vv8 = *(const ush8*)(base + 2048);
      }
      *(ush8*)&Kb[row][cc] = kv8;
      #pragma unroll
      for (int e = 0; e < 8; ++e) Vt[cc + e][row] = vv8[e];
    }
    __syncthreads();

    f32x4 s[4];
    #pragma unroll
    for (int kt = 0; kt < 4; ++kt) {
      bf16x8 bk0 = *(const bf16x8*)&Kb[kt * 16 + l15][l4 * 8];
      bf16x8 bk1 = *(const bf16x8*)&Kb[kt * 16 + l15][32 + l4 * 8];
      f32x4 t = __builtin_amdgcn_mfma_f32_16x16x32_bf16(aq0, bk0, fz, 0, 0, 0);
      s[kt]   = __builtin_amdgcn_mfma_f32_16x16x32_bf16(aq1, bk1, t,  0, 0, 0);
    }

    #pragma unroll
    for (int r = 0; r < 4; ++r) {
      const int qg = qb + w * 16 + l4 * 4 + r;
      float rm = -3.0e38f;
      #pragma unroll
      for (int kt = 0; kt < 4; ++kt) {
        const int kg = kb + kt * 16 + l15;
        const bool ok = (kg <= qg) && (kg + WIN_ > qg);
        rm = fmaxf(rm, ok ? s[kt][r] : -3.0e38f);
      }
      rm = fmaxf(rm, __shfl_xor(rm, 1));
      rm = fmaxf(rm, __shfl_xor(rm, 2));
      rm = fmaxf(rm, __shfl_xor(rm, 4));
      rm = fmaxf(rm, __shfl_xor(rm, 8));
      const float mn = fmaxf(m_[r], rm);
      const float sf = __expf(m_[r] - mn);
      m_[r] = mn;
      float ps = 0.f;
      #pragma unroll
      for (int kt = 0; kt < 4; ++kt) {
        const int kg = kb + kt * 16 + l15;
        const bool ok = (kg <= qg) && (kg + WIN_ > qg);
        const float p = ok ? __expf(s[kt][r] - mn) : 0.f;
        ps += p;
        Ps[w][l4 * 4 + r][kt * 16 + l15] = f2bf(p);
      }
      ps += __shfl_xor(ps, 1);
      ps += __shfl_xor(ps, 2);
      ps += __shfl_xor(ps, 4);
      ps += __shfl_xor(ps, 8);
      ls[r] = ls[r] * sf + ps;
      #pragma unroll
      for (int j = 0; j < 4; ++j) acc_o[j][r] *= sf;
    }

    #pragma unroll
    for (int ks = 0; ks < 2; ++ks) {
      bf16x8 pa = *(const bf16x8*)&Ps[w][l15][ks * 32 + l4 * 8];
      #pragma unroll
      for (int j = 0; j < 4; ++j) {
        bf16x8 vb = *(const bf16x8*)&Vt[j * 16 + l15][ks * 32 + l4 * 8];
        acc_o[j] = __builtin_amdgcn_mfma_f32_16x16x32_bf16(pa, vb, acc_o[j], 0, 0, 0);
      }
    }
    __syncthreads();
  }

  #pragma unroll
  for (int r = 0; r < 4; ++r) {
    const int qg = qb + w * 16 + l4 * 4 + r;
    if (qg < L_) {
      const float inv = 1.0f / ls[r];
      unsigned short* dst = ctx + ((size_t)(b * L_ + qg)) * 1024 + h * 64 + l15;
      #pragma unroll
      for (int j = 0; j < 4; ++j) dst[j * 16] = f2bf(acc_o[j][r] * inv);
    }
  }
}

// ---------------- launch ----------------
extern "C" void kernel_launch(void* const* d_in, const int* in_sizes, int n_in,
                              void* d_out, int out_size, void* d_ws, size_t ws_size,
                              hipStream_t stream) {
  (void)in_sizes; (void)n_in; (void)out_size; (void)ws_size;
  const float* x    = (const float*)d_in[0];
  const float* pmem = (const float*)d_in[1];
  const float* mW1  = (const float*)d_in[2];
  const float* mb1  = (const float*)d_in[3];
  const float* mW2  = (const float*)d_in[4];
  const float* mb2  = (const float*)d_in[5];
  const float* ln1g = (const float*)d_in[6];
  const float* ln1b = (const float*)d_in[7];
  const float* Wqkv = (const float*)d_in[8];
  const float* bqkv = (const float*)d_in[9];
  const float* Wo   = (const float*)d_in[10];
  const float* bo   = (const float*)d_in[11];
  const float* ln2g = (const float*)d_in[12];
  const float* ln2b = (const float*)d_in[13];
  const float* fW1  = (const float*)d_in[14];
  const float* fb1  = (const float*)d_in[15];
  const float* fW2  = (const float*)d_in[16];
  const float* fb2  = (const float*)d_in[17];
  float* outp = (float*)d_out;
  char* ws = (char*)d_ws;

  // workspace layout (bytes); total ~134.6 MB
  unsigned short* w1b   = (unsigned short*)(ws + 0ull);          // 8 MB
  unsigned short* w2b   = (unsigned short*)(ws + 8388608ull);    // 8 MB
  unsigned short* wqkvb = (unsigned short*)(ws + 16777216ull);   // 6 MB
  unsigned short* wob   = (unsigned short*)(ws + 23068672ull);   // 2 MB
  unsigned short* fw1b  = (unsigned short*)(ws + 25165824ull);   // 8 MB
  unsigned short* fw2b  = (unsigned short*)(ws + 33554432ull);   // 8 MB
  const size_t S = 41943040ull;
  float* aug  = (float*)(ws + S);                                // 4104x1024 f32
  float* hres = (float*)(ws + S + 16809984ull);                  // 4104x1024 f32
  unsigned short* hlnbuf = (unsigned short*)(ws + S + 33619968ull); // 4224x1024 bf16 (shared hln/ctx/hln2)
  char* R = ws + S + 42270720ull;                                // 50.4 MB shared region
  unsigned short* xb   = (unsigned short*)(R);                   // stage 1   (2048x1024)
  unsigned short* h1   = (unsigned short*)(R + 4194304ull);      // stages 1-2 (2048x4096, ends R+20971520)
  unsigned short* qkvb = (unsigned short*)(R);                   // stages 5-6 (4104x3072 bf16)
  unsigned short* f1   = (unsigned short*)(R + 15826944ull);     // stages 9-10 (4224x4096)
  unsigned short* hln  = hlnbuf;
  unsigned short* ctxb = hlnbuf;
  unsigned short* hln2 = hlnbuf;
  // gemm2 split-K partials (4 x 2048x1024 f32), DISJOINT from h1 (its input):
  // z0 @ hres, z1 @ hres+8.4M, z2 @ R+20971520 (past h1's end), z3 @ +8.4M.
  float* g2p = hres;
  const long long G2S  = 8404992LL;         // (z&1) stride
  const long long G2S2 = 46432256LL;        // (z>>1) stride: hres -> R+20971520
  // gemm10 split-K partials (4 x 4104x1024 bf16), two-stride:
  // z0 @ aug, z1 @ aug+8.4M, z2 @ hlnbuf, z3 @ hlnbuf+8.4M
  const long long Z10a = 8404992LL;         // (z&1) stride
  const long long Z10b = 33619968LL;        // (z>>1) stride (aug -> hlnbuf)

  const int BT = B_ * T_;   // 2048
  const int BL = B_ * L_;   // 4104
  const int NE4 = B_ * L_ * D_ / 4;

  // 0. all fp32->bf16 conversions in one launch
  cvt7_k<<<dim3((MH_ * D_ / 4 + 255) / 256, 7), 256, 0, stream>>>(
      x, xb, B_ * T_ * D_,  mW1, w1b, MH_ * D_,  mW2, w2b, D_ * MH_,
      Wqkv, wqkvb, 3 * D_ * D_,  Wo, wob, D_ * D_,
      fW1, fw1b, FF_ * D_,  fW2, fw2b, D_ * FF_);

  // 1. h1 = relu(x @ mW1^T + mb1), bf16   [fat 128x256, 8 waves]
  gemm_bt_k<1, 1, 0, 4, 4, 2, 4, 1, 0, 0><<<dim3(MH_ / 256, BT / 128), 512, 0, stream>>>(xb, w1b, mb1, nullptr, h1, BT, MH_, D_, D_, 0, 0);
  // 2. split-K z=4: partials = h1 @ mW2^T (K-quarters), raw fp32 [128x128, SWZ]
  gemm_bt_k<0, 0, 0, 4, 4, 2, 2, 1, 1, 1><<<dim3(D_ / 128, BT / 128, 4), 256, 0, stream>>>(h1, w2b, nullptr, nullptr, g2p, BT, D_, MH_ / 4, MH_, G2S, G2S2);
  // 3+4. aug = concat(pers, sum(p)+mb2, x); hln = LN1(aug)
  concat_ln1_k<<<dim3(BL), 256, 0, stream>>>(x, pmem,
      g2p, (float*)((char*)g2p + G2S), (float*)((char*)g2p + G2S2), (float*)((char*)g2p + G2S + G2S2),
      mb2, ln1g, ln1b, aug, hln);
  // 5. qkv = hln @ Wqkv^T + bqkv, bf16    [fat 128x256, 8 waves]
  gemm_bt_k<0, 1, 0, 4, 4, 2, 4, 1, 0, 0><<<dim3(3 * D_ / 256, (BL + 127) / 128), 512, 0, stream>>>(hln, wqkvb, bqkv, nullptr, qkvb, BL, 3 * D_, D_, D_, 0, 0);
  // 6. ctx = sliding-window attention (MFMA), bf16 [128 queries/block]
  attn_k<<<dim3((L_ + 127) / 128, H_, B_), 512, 0, stream>>>(qkvb, ctxb);
  // 7. hres = aug + ctx @ Wo^T + bo, fp32 [128x64, KS=1]
  gemm_bt_k<0, 0, 1, 2, 4, 4, 1, 1, 0, 0><<<dim3(D_ / 64, (BL + 127) / 128), 256, 0, stream>>>(ctxb, wob, bo, aug, hres, BL, D_, D_, D_, 0, 0);
  // 8. hln2 = LN2(hres), bf16
  layernorm_k<<<dim3(BL), 256, 0, stream>>>(hres, ln2g, ln2b, hln2);
  // 9. f1 = gelu(hln2 @ fW1^T + fb1), bf16 [fat 128x256, 8 waves]
  gemm_bt_k<2, 1, 0, 4, 4, 2, 4, 1, 0, 0><<<dim3(FF_ / 256, (BL + 127) / 128), 512, 0, stream>>>(hln2, fw1b, fb1, nullptr, f1, BL, FF_, D_, D_, 0, 0);
  // 10a. split-K z=4: bf16 partials = f1 @ fW2^T (K-quarters) [fat 128x256, 8 waves]
  gemm_bt_k<0, 1, 0, 4, 4, 2, 4, 1, 1, 0><<<dim3(D_ / 256, (BL + 127) / 128, 4), 512, 0, stream>>>(f1, fw2b, nullptr, nullptr, (void*)aug, BL, D_, FF_ / 4, FF_, Z10a, Z10b);
  // 10b. out = sum(bf16 partials) + fb2 + hres
  reduce10_k<<<dim3((NE4 + 255) / 256), 256, 0, stream>>>(
      (const unsigned short*)aug,
      (const unsigned short*)((char*)aug + Z10a),
      (const unsigned short*)((char*)aug + Z10b),
      (const unsigned short*)((char*)aug + Z10a + Z10b),
      hres, fb2, outp);
}